// Round 9
// baseline (129.159 us; speedup 1.0000x reference)
//
#include <hip/hip_runtime.h>
#include <math.h>

#define NLAT 46
#define NLON 90
#define CH   256
#define HW   (NLAT*NLON)   // 4140
#define HWP  4160
#define HWT  32            // hw rows per proj block
#define NHT  130           // hw tiles
#define XSTR 264           // LDS row stride (ushorts)

// attn schedule: heavy lats {0,1,44,45} sliced 45-wo per XCD; light lats banded.
#define LIGHT_PER_XCD 473
#define SLOTS_PER_XCD (45 + LIGHT_PER_XCD)

typedef __attribute__((ext_vector_type(8))) short short8;
typedef __attribute__((ext_vector_type(4))) float floatx4;

// packed RNE f32x2 -> bf16x2; uses v_cvt_pk_bf16_f32 when available
__device__ __forceinline__ ushort2 f2bf2(float a, float b){
#if __has_builtin(__builtin_amdgcn_cvt_pk_bf16_f32)
  typedef __attribute__((ext_vector_type(2))) __bf16 bf16x2;
  bf16x2 r = __builtin_amdgcn_cvt_pk_bf16_f32(a, b);
  return *reinterpret_cast<ushort2*>(&r);
#else
  __bf16 ha = (__bf16)a;
  __bf16 hb = (__bf16)b;
  ushort2 o;
  o.x = *reinterpret_cast<ushort*>(&ha);
  o.y = *reinterpret_cast<ushort*>(&hb);
  return o;
#endif
}
__device__ __forceinline__ float bf2fs(short s){
  return __uint_as_float(((uint)(ushort)s) << 16);
}

__device__ __forceinline__ int lower_bound_i(const int* __restrict__ a, int n, int key){
  int lo = 0, hi = n;
  while (lo < hi){ int mid = (lo + hi) >> 1; if (a[mid] < key) lo = mid + 1; else hi = mid; }
  return lo;
}

// Fused cast+transpose+GEMM: Out[hw][kout] = sum_c W[kout][c]*X[c][hw] + bias.
// Block = 32 hw x 256 kout; 4 waves each own 64 kout. X transposed through
// LDS (bf16); W fp32 frags loaded from L2 and cast inline (packed cvt).
__global__ __launch_bounds__(256) void fproj_kernel(
    const float* __restrict__ qo, const float* __restrict__ ki, const float* __restrict__ vi,
    const float* __restrict__ qw, const float* __restrict__ kw, const float* __restrict__ vw,
    const float* __restrict__ qb, const float* __restrict__ kb, const float* __restrict__ vb,
    ushort* __restrict__ qP, ushort* __restrict__ kP, ushort* __restrict__ vP)
{
  const float* X; const float* Wf; const float* Bias; ushort* Out;
  if (blockIdx.y == 0){ X = qo; Wf = qw; Bias = qb; Out = qP; }
  else if (blockIdx.y == 1){ X = ki; Wf = kw; Bias = kb; Out = kP; }
  else { X = vi; Wf = vw; Bias = vb; Out = vP; }

  __shared__ ushort Xs[HWT][XSTR];

  const int tid = threadIdx.x;
  const int hw0 = blockIdx.x * HWT;

  // ---- stage: X[c][hw] fp32 -> Xs[hwL][c] bf16 (packed cvt) ----
  {
    int hwL = tid & 31;
    int cb  = tid >> 5;              // 0..7, owns c in [cb*32, cb*32+32)
    int hw  = hw0 + hwL;
    bool ok = hw < HW;
    const float* Xp = X + (size_t)(cb*32)*HW + (ok ? hw : 0);
    #pragma unroll
    for (int g = 0; g < 4; g++){
      float f[8];
      #pragma unroll
      for (int u = 0; u < 8; u++)
        f[u] = ok ? Xp[(size_t)(g*8 + u)*HW] : 0.f;
      short8 pk;
      #pragma unroll
      for (int u = 0; u < 8; u += 2){
        ushort2 p = f2bf2(f[u], f[u+1]);
        pk[u] = (short)p.x; pk[u+1] = (short)p.y;
      }
      *(short8*)(&Xs[hwL][cb*32 + g*8]) = pk;
    }
  }
  __syncthreads();

  const int lane = tid & 63;
  const int wave = tid >> 6;
  const int lm = lane & 15;
  const int lq = lane >> 4;
  const int kout_w = wave * 64;

  const float* Apf = Wf + (size_t)(kout_w + lm)*CH + lq*8;

  floatx4 acc[4][2];
  #pragma unroll
  for (int i = 0; i < 4; i++)
    #pragma unroll
    for (int j = 0; j < 2; j++) acc[i][j] = (floatx4){0,0,0,0};

  #pragma unroll
  for (int k0 = 0; k0 < 8; k0++){
    short8 a[4], b[2];
    #pragma unroll
    for (int i = 0; i < 4; i++){
      const float* p = Apf + (size_t)i*16*CH + k0*32;
      float4 w0 = *(const float4*)p;
      float4 w1 = *(const float4*)(p + 4);
      ushort2 p0 = f2bf2(w0.x, w0.y);
      ushort2 p1 = f2bf2(w0.z, w0.w);
      ushort2 p2 = f2bf2(w1.x, w1.y);
      ushort2 p3 = f2bf2(w1.z, w1.w);
      a[i][0] = (short)p0.x; a[i][1] = (short)p0.y;
      a[i][2] = (short)p1.x; a[i][3] = (short)p1.y;
      a[i][4] = (short)p2.x; a[i][5] = (short)p2.y;
      a[i][6] = (short)p3.x; a[i][7] = (short)p3.y;
    }
    #pragma unroll
    for (int j = 0; j < 2; j++)
      b[j] = *(const short8*)(&Xs[j*16 + lm][lq*8 + k0*32]);
    #pragma unroll
    for (int i = 0; i < 4; i++)
      #pragma unroll
      for (int j = 0; j < 2; j++)
        acc[i][j] = __builtin_amdgcn_mfma_f32_16x16x32_bf16(a[i], b[j], acc[i][j], 0, 0, 0);
  }

  // C/D: col(lane&15)=hw, row(lq*4+r)=kout
  #pragma unroll
  for (int i = 0; i < 4; i++){
    int kout = kout_w + i*16 + lq*4;
    float4 bias = *(const float4*)(Bias + kout);
    #pragma unroll
    for (int j = 0; j < 2; j++){
      int hw = hw0 + j*16 + lm;
      if (hw < HW){
        ushort2 o0 = f2bf2(acc[i][j][0] + bias.x, acc[i][j][1] + bias.y);
        ushort2 o1 = f2bf2(acc[i][j][2] + bias.z, acc[i][j][3] + bias.w);
        ushort4 o; o.x = o0.x; o.y = o0.y; o.z = o1.x; o.w = o1.y;
        *(ushort4*)(Out + (size_t)hw*CH + kout) = o;
      }
    }
  }
}

// Block per (t,wo). Lane = (visit-slot g=lane>>4, channel-group gl=lane&15):
// 16 visit-slots/block, 16 channels/lane, 4 shuffle levels/dot, 2x unrolled.
__global__ __launch_bounds__(256) void attn_kernel(
    const ushort* __restrict__ qP, const ushort* __restrict__ kP, const ushort* __restrict__ vP,
    const float* __restrict__ quad_w, const int* __restrict__ row_ids,
    const int* __restrict__ col_idx, int nnz, float* __restrict__ out)
{
  const int bid  = blockIdx.x;
  const int xcd  = bid & 7;
  const int slot = bid >> 3;

  int t, wo;
  if (slot < 45){
    int hu   = xcd * 45 + slot;
    int hidx = hu / 90;
    t  = (hidx < 2) ? hidx : 42 + hidx;
    wo = hu - hidx * 90;
  } else {
    int lu = xcd * LIGHT_PER_XCD + (slot - 45);
    if (lu >= 42 * NLON) return;
    int li = lu / NLON;
    t  = li + 2;
    wo = lu - li * NLON;
  }

  const int tid  = threadIdx.x;
  const int lane = tid & 63;
  const int wave = tid >> 6;
  const int g    = lane >> 4;
  const int gl   = lane & 15;

  const int start = lower_bound_i(row_ids, nnz, t);
  const int end   = lower_bound_i(row_ids, nnz, t + 1);

  // q channels [gl*16, gl*16+16)
  float qf[16];
  {
    const ushort* qrow = qP + (size_t)(t * NLON + wo) * CH + gl*16;
    short8 q0 = *(const short8*)(qrow);
    short8 q1 = *(const short8*)(qrow + 8);
    #pragma unroll
    for (int u = 0; u < 8; u++){ qf[u] = bf2fs(q0[u]); qf[8+u] = bf2fs(q1[u]); }
  }

  float den = 0.f;
  float acc[16];
  #pragma unroll
  for (int u = 0; u < 16; u++) acc[u] = 0.f;

  int n0 = start + wave*4 + g;
  for (; n0 + 16 < end; n0 += 32){
    // visit A
    int ciA = col_idx[n0];
    int hiA = ciA / NLON;
    int wiA = ciA - hiA*NLON + wo; if (wiA >= NLON) wiA -= NLON;
    size_t offA = ((size_t)hiA*NLON + wiA) * CH + gl*16;
    // visit B
    int ciB = col_idx[n0 + 16];
    int hiB = ciB / NLON;
    int wiB = ciB - hiB*NLON + wo; if (wiB >= NLON) wiB -= NLON;
    size_t offB = ((size_t)hiB*NLON + wiB) * CH + gl*16;

    const short8* kpA = (const short8*)(kP + offA);
    const short8* kpB = (const short8*)(kP + offB);
    short8 kA0 = kpA[0], kA1 = kpA[1];
    short8 kB0 = kpB[0], kB1 = kpB[1];
    float sA = 0.f, sB = 0.f;
    #pragma unroll
    for (int u = 0; u < 8; u++){
      sA += qf[u]   * bf2fs(kA0[u]);
      sA += qf[8+u] * bf2fs(kA1[u]);
      sB += qf[u]   * bf2fs(kB0[u]);
      sB += qf[8+u] * bf2fs(kB1[u]);
    }
    #pragma unroll
    for (int o = 1; o <= 8; o <<= 1){
      sA += __shfl_xor(sA, o, 64);
      sB += __shfl_xor(sB, o, 64);
    }
    float eA = __expf(sA) * quad_w[hiA];
    float eB = __expf(sB) * quad_w[hiB];
    const short8* vpA = (const short8*)(vP + offA);
    const short8* vpB = (const short8*)(vP + offB);
    short8 vA0 = vpA[0], vA1 = vpA[1];
    short8 vB0 = vpB[0], vB1 = vpB[1];
    den += eA + eB;
    #pragma unroll
    for (int u = 0; u < 8; u++){
      acc[u]   += eA * bf2fs(vA0[u]) + eB * bf2fs(vB0[u]);
      acc[8+u] += eA * bf2fs(vA1[u]) + eB * bf2fs(vB1[u]);
    }
  }
  if (n0 < end){
    int ci = col_idx[n0];
    int hi = ci / NLON;
    int wi = ci - hi*NLON + wo; if (wi >= NLON) wi -= NLON;
    size_t off = ((size_t)hi*NLON + wi) * CH + gl*16;
    const short8* kp8 = (const short8*)(kP + off);
    short8 k0 = kp8[0], k1 = kp8[1];
    float s = 0.f;
    #pragma unroll
    for (int u = 0; u < 8; u++){
      s += qf[u]   * bf2fs(k0[u]);
      s += qf[8+u] * bf2fs(k1[u]);
    }
    #pragma unroll
    for (int o = 1; o <= 8; o <<= 1) s += __shfl_xor(s, o, 64);
    float e = __expf(s) * quad_w[hi];
    const short8* vp8 = (const short8*)(vP + off);
    short8 v0 = vp8[0], v1 = vp8[1];
    den += e;
    #pragma unroll
    for (int u = 0; u < 8; u++){
      acc[u]   += e * bf2fs(v0[u]);
      acc[8+u] += e * bf2fs(v1[u]);
    }
  }

  // merge the 4 visit-slots within the wave
  #pragma unroll
  for (int u = 0; u < 16; u++){
    acc[u] += __shfl_xor(acc[u], 16, 64);
    acc[u] += __shfl_xor(acc[u], 32, 64);
  }
  den += __shfl_xor(den, 16, 64);
  den += __shfl_xor(den, 32, 64);

  __shared__ float sden[4];
  __shared__ float sacc[4][CH];
  if (lane == 0) sden[wave] = den;
  if (g == 0){
    #pragma unroll
    for (int u = 0; u < 16; u++) sacc[wave][gl*16 + u] = acc[u];
  }
  __syncthreads();

  const float D   = sden[0] + sden[1] + sden[2] + sden[3];
  const float num = sacc[0][tid] + sacc[1][tid] + sacc[2][tid] + sacc[3][tid];
  out[(size_t)tid * HW + t * NLON + wo] = num / D;
}

extern "C" void kernel_launch(void* const* d_in, const int* in_sizes, int n_in,
                              void* d_out, int out_size, void* d_ws, size_t ws_size,
                              hipStream_t stream)
{
  const float* qo   = (const float*)d_in[0];
  const float* ki   = (const float*)d_in[1];
  const float* vi   = (const float*)d_in[2];
  const float* qw   = (const float*)d_in[3];
  const float* kw   = (const float*)d_in[4];
  const float* vw   = (const float*)d_in[5];
  const float* qb   = (const float*)d_in[6];
  const float* kb   = (const float*)d_in[7];
  const float* vb   = (const float*)d_in[8];
  const float* quad = (const float*)d_in[9];
  const int* row_ids = (const int*)d_in[10];
  const int* col_idx = (const int*)d_in[11];
  const int nnz = in_sizes[10];

  ushort* ws = (ushort*)d_ws;
  const size_t TSZ = (size_t)HWP * CH;
  ushort* qP = ws;  ushort* kP = qP + TSZ;  ushort* vP = kP + TSZ;

  fproj_kernel<<<dim3(NHT, 3), 256, 0, stream>>>(qo, ki, vi, qw, kw, vw, qb, kb, vb, qP, kP, vP);
  attn_kernel<<<dim3(8 * SLOTS_PER_XCD), 256, 0, stream>>>(qP, kP, vP, quad, row_ids, col_idx, nnz, (float*)d_out);
}

// Round 10
// 126.677 us; speedup vs baseline: 1.0196x; 1.0196x over previous
//
#include <hip/hip_runtime.h>
#include <math.h>

#define NLAT 46
#define NLON 90
#define CH   256
#define HW   (NLAT*NLON)   // 4140
#define HWP  4160
#define HWT  32            // hw rows per proj block
#define NHT  130           // hw tiles
#define XSTR 264           // LDS row stride (ushorts)

// attn schedule: heavy lats {0,1,44,45} sliced 45-wo per XCD; light lats banded.
#define LIGHT_PER_XCD 473
#define SLOTS_PER_XCD (45 + LIGHT_PER_XCD)

typedef __attribute__((ext_vector_type(8))) short short8;
typedef __attribute__((ext_vector_type(4))) float floatx4;

// packed RNE f32x2 -> bf16x2; uses v_cvt_pk_bf16_f32 when available
__device__ __forceinline__ ushort2 f2bf2(float a, float b){
#if __has_builtin(__builtin_amdgcn_cvt_pk_bf16_f32)
  typedef __attribute__((ext_vector_type(2))) __bf16 bf16x2;
  bf16x2 r = __builtin_amdgcn_cvt_pk_bf16_f32(a, b);
  return *reinterpret_cast<ushort2*>(&r);
#else
  __bf16 ha = (__bf16)a;
  __bf16 hb = (__bf16)b;
  ushort2 o;
  o.x = *reinterpret_cast<ushort*>(&ha);
  o.y = *reinterpret_cast<ushort*>(&hb);
  return o;
#endif
}
__device__ __forceinline__ float bf2fs(short s){
  return __uint_as_float(((uint)(ushort)s) << 16);
}

__device__ __forceinline__ int lower_bound_i(const int* __restrict__ a, int n, int key){
  int lo = 0, hi = n;
  while (lo < hi){ int mid = (lo + hi) >> 1; if (a[mid] < key) lo = mid + 1; else hi = mid; }
  return lo;
}

// Fused cast+transpose+GEMM: Out[hw][kout] = sum_c W[kout][c]*X[c][hw] + bias.
// Block = 32 hw x 256 kout; 4 waves each own 64 kout. X transposed through
// LDS (bf16); W fp32 frags loaded from L2 and cast inline (packed cvt).
__global__ __launch_bounds__(256) void fproj_kernel(
    const float* __restrict__ qo, const float* __restrict__ ki, const float* __restrict__ vi,
    const float* __restrict__ qw, const float* __restrict__ kw, const float* __restrict__ vw,
    const float* __restrict__ qb, const float* __restrict__ kb, const float* __restrict__ vb,
    ushort* __restrict__ qP, ushort* __restrict__ kP, ushort* __restrict__ vP)
{
  const float* X; const float* Wf; const float* Bias; ushort* Out;
  if (blockIdx.y == 0){ X = qo; Wf = qw; Bias = qb; Out = qP; }
  else if (blockIdx.y == 1){ X = ki; Wf = kw; Bias = kb; Out = kP; }
  else { X = vi; Wf = vw; Bias = vb; Out = vP; }

  __shared__ ushort Xs[HWT][XSTR];

  const int tid = threadIdx.x;
  const int hw0 = blockIdx.x * HWT;

  // ---- stage: X[c][hw] fp32 -> Xs[hwL][c] bf16 (packed cvt) ----
  {
    int hwL = tid & 31;
    int cb  = tid >> 5;              // 0..7, owns c in [cb*32, cb*32+32)
    int hw  = hw0 + hwL;
    bool ok = hw < HW;
    const float* Xp = X + (size_t)(cb*32)*HW + (ok ? hw : 0);
    #pragma unroll
    for (int g = 0; g < 4; g++){
      float f[8];
      #pragma unroll
      for (int u = 0; u < 8; u++)
        f[u] = ok ? Xp[(size_t)(g*8 + u)*HW] : 0.f;
      short8 pk;
      #pragma unroll
      for (int u = 0; u < 8; u += 2){
        ushort2 p = f2bf2(f[u], f[u+1]);
        pk[u] = (short)p.x; pk[u+1] = (short)p.y;
      }
      *(short8*)(&Xs[hwL][cb*32 + g*8]) = pk;
    }
  }
  __syncthreads();

  const int lane = tid & 63;
  const int wave = tid >> 6;
  const int lm = lane & 15;
  const int lq = lane >> 4;
  const int kout_w = wave * 64;

  const float* Apf = Wf + (size_t)(kout_w + lm)*CH + lq*8;

  floatx4 acc[4][2];
  #pragma unroll
  for (int i = 0; i < 4; i++)
    #pragma unroll
    for (int j = 0; j < 2; j++) acc[i][j] = (floatx4){0,0,0,0};

  #pragma unroll
  for (int k0 = 0; k0 < 8; k0++){
    short8 a[4], b[2];
    #pragma unroll
    for (int i = 0; i < 4; i++){
      const float* p = Apf + (size_t)i*16*CH + k0*32;
      float4 w0 = *(const float4*)p;
      float4 w1 = *(const float4*)(p + 4);
      ushort2 p0 = f2bf2(w0.x, w0.y);
      ushort2 p1 = f2bf2(w0.z, w0.w);
      ushort2 p2 = f2bf2(w1.x, w1.y);
      ushort2 p3 = f2bf2(w1.z, w1.w);
      a[i][0] = (short)p0.x; a[i][1] = (short)p0.y;
      a[i][2] = (short)p1.x; a[i][3] = (short)p1.y;
      a[i][4] = (short)p2.x; a[i][5] = (short)p2.y;
      a[i][6] = (short)p3.x; a[i][7] = (short)p3.y;
    }
    #pragma unroll
    for (int j = 0; j < 2; j++)
      b[j] = *(const short8*)(&Xs[j*16 + lm][lq*8 + k0*32]);
    #pragma unroll
    for (int i = 0; i < 4; i++)
      #pragma unroll
      for (int j = 0; j < 2; j++)
        acc[i][j] = __builtin_amdgcn_mfma_f32_16x16x32_bf16(a[i], b[j], acc[i][j], 0, 0, 0);
  }

  // C/D: col(lane&15)=hw, row(lq*4+r)=kout
  #pragma unroll
  for (int i = 0; i < 4; i++){
    int kout = kout_w + i*16 + lq*4;
    float4 bias = *(const float4*)(Bias + kout);
    #pragma unroll
    for (int j = 0; j < 2; j++){
      int hw = hw0 + j*16 + lm;
      if (hw < HW){
        ushort2 o0 = f2bf2(acc[i][j][0] + bias.x, acc[i][j][1] + bias.y);
        ushort2 o1 = f2bf2(acc[i][j][2] + bias.z, acc[i][j][3] + bias.w);
        ushort4 o; o.x = o0.x; o.y = o0.y; o.z = o1.x; o.w = o1.y;
        *(ushort4*)(Out + (size_t)hw*CH + kout) = o;
      }
    }
  }
}

// Block per (t,wo). Lane = (visit-slot g=lane>>4, channel-group gl=lane&15):
// 16 visit-slots/block, 16 channels/lane, 4 shuffle levels/dot.
// Single-visit loop (R6 form): lower VGPR pressure beats 2x-unroll ILP here.
__global__ __launch_bounds__(256) void attn_kernel(
    const ushort* __restrict__ qP, const ushort* __restrict__ kP, const ushort* __restrict__ vP,
    const float* __restrict__ quad_w, const int* __restrict__ row_ids,
    const int* __restrict__ col_idx, int nnz, float* __restrict__ out)
{
  const int bid  = blockIdx.x;
  const int xcd  = bid & 7;
  const int slot = bid >> 3;

  int t, wo;
  if (slot < 45){
    int hu   = xcd * 45 + slot;
    int hidx = hu / 90;
    t  = (hidx < 2) ? hidx : 42 + hidx;
    wo = hu - hidx * 90;
  } else {
    int lu = xcd * LIGHT_PER_XCD + (slot - 45);
    if (lu >= 42 * NLON) return;
    int li = lu / NLON;
    t  = li + 2;
    wo = lu - li * NLON;
  }

  const int tid  = threadIdx.x;
  const int lane = tid & 63;
  const int wave = tid >> 6;
  const int g    = lane >> 4;
  const int gl   = lane & 15;

  const int start = lower_bound_i(row_ids, nnz, t);
  const int end   = lower_bound_i(row_ids, nnz, t + 1);

  // q channels [gl*16, gl*16+16)
  float qf[16];
  {
    const ushort* qrow = qP + (size_t)(t * NLON + wo) * CH + gl*16;
    short8 q0 = *(const short8*)(qrow);
    short8 q1 = *(const short8*)(qrow + 8);
    #pragma unroll
    for (int u = 0; u < 8; u++){ qf[u] = bf2fs(q0[u]); qf[8+u] = bf2fs(q1[u]); }
  }

  float den = 0.f;
  float acc[16];
  #pragma unroll
  for (int u = 0; u < 16; u++) acc[u] = 0.f;

  for (int n0 = start + wave*4 + g; n0 < end; n0 += 16){
    int ci = col_idx[n0];
    int hi = ci / NLON;
    int wi = ci - hi*NLON + wo; if (wi >= NLON) wi -= NLON;
    size_t off = ((size_t)hi*NLON + wi) * CH + gl*16;

    const short8* kp8 = (const short8*)(kP + off);
    short8 k0 = kp8[0], k1 = kp8[1];
    float s = 0.f;
    #pragma unroll
    for (int u = 0; u < 8; u++){
      s += qf[u]   * bf2fs(k0[u]);
      s += qf[8+u] * bf2fs(k1[u]);
    }
    s += __shfl_xor(s, 1, 64);
    s += __shfl_xor(s, 2, 64);
    s += __shfl_xor(s, 4, 64);
    s += __shfl_xor(s, 8, 64);

    float e = __expf(s) * quad_w[hi];
    const short8* vp8 = (const short8*)(vP + off);
    short8 v0 = vp8[0], v1 = vp8[1];
    den += e;
    #pragma unroll
    for (int u = 0; u < 8; u++){
      acc[u]   += e * bf2fs(v0[u]);
      acc[8+u] += e * bf2fs(v1[u]);
    }
  }

  // merge the 4 visit-slots within the wave
  #pragma unroll
  for (int u = 0; u < 16; u++){
    acc[u] += __shfl_xor(acc[u], 16, 64);
    acc[u] += __shfl_xor(acc[u], 32, 64);
  }
  den += __shfl_xor(den, 16, 64);
  den += __shfl_xor(den, 32, 64);

  __shared__ float sden[4];
  __shared__ float sacc[4][CH];
  if (lane == 0) sden[wave] = den;
  if (g == 0){
    #pragma unroll
    for (int u = 0; u < 16; u++) sacc[wave][gl*16 + u] = acc[u];
  }
  __syncthreads();

  const float D   = sden[0] + sden[1] + sden[2] + sden[3];
  const float num = sacc[0][tid] + sacc[1][tid] + sacc[2][tid] + sacc[3][tid];
  out[(size_t)tid * HW + t * NLON + wo] = num / D;
}

extern "C" void kernel_launch(void* const* d_in, const int* in_sizes, int n_in,
                              void* d_out, int out_size, void* d_ws, size_t ws_size,
                              hipStream_t stream)
{
  const float* qo   = (const float*)d_in[0];
  const float* ki   = (const float*)d_in[1];
  const float* vi   = (const float*)d_in[2];
  const float* qw   = (const float*)d_in[3];
  const float* kw   = (const float*)d_in[4];
  const float* vw   = (const float*)d_in[5];
  const float* qb   = (const float*)d_in[6];
  const float* kb   = (const float*)d_in[7];
  const float* vb   = (const float*)d_in[8];
  const float* quad = (const float*)d_in[9];
  const int* row_ids = (const int*)d_in[10];
  const int* col_idx = (const int*)d_in[11];
  const int nnz = in_sizes[10];

  ushort* ws = (ushort*)d_ws;
  const size_t TSZ = (size_t)HWP * CH;
  ushort* qP = ws;  ushort* kP = qP + TSZ;  ushort* vP = kP + TSZ;

  fproj_kernel<<<dim3(NHT, 3), 256, 0, stream>>>(qo, ki, vi, qw, kw, vw, qb, kb, vb, qP, kP, vP);
  attn_kernel<<<dim3(8 * SLOTS_PER_XCD), 256, 0, stream>>>(qP, kP, vP, quad, row_ids, col_idx, nnz, (float*)d_out);
}

// Round 11
// 122.681 us; speedup vs baseline: 1.0528x; 1.0326x over previous
//
#include <hip/hip_runtime.h>
#include <math.h>

#define NLAT 46
#define NLON 90
#define CH   256
#define HW   (NLAT*NLON)   // 4140
#define HWP  4160
#define HWT  32            // hw rows per proj block
#define NHT  130           // hw tiles
#define XSTR 264           // LDS row stride (ushorts)

// attn schedule: heavy lats {0,1,44,45} sliced 45-wo per XCD; light lats banded.
#define LIGHT_PER_XCD 473
#define SLOTS_PER_XCD (45 + LIGHT_PER_XCD)

typedef __attribute__((ext_vector_type(8))) short short8;
typedef __attribute__((ext_vector_type(4))) float floatx4;

// manual RNE f32 -> bf16 (measured faster than cvt_pk builtin path on this
// ROCm build -- R6=121.1us vs R10=126.7us, only diff was this helper)
__device__ __forceinline__ ushort f2bf(float f){
  uint u = __float_as_uint(f);
  u += 0x7fff + ((u >> 16) & 1);      // RNE
  return (ushort)(u >> 16);
}
__device__ __forceinline__ float bf2fs(short s){
  return __uint_as_float(((uint)(ushort)s) << 16);
}

__device__ __forceinline__ int lower_bound_i(const int* __restrict__ a, int n, int key){
  int lo = 0, hi = n;
  while (lo < hi){ int mid = (lo + hi) >> 1; if (a[mid] < key) lo = mid + 1; else hi = mid; }
  return lo;
}

// Fused cast+transpose+GEMM: Out[hw][kout] = sum_c W[kout][c]*X[c][hw] + bias.
// Block = 32 hw x 256 kout; 4 waves each own 64 kout. X transposed through
// LDS (bf16); W fp32 frags loaded from L2 and cast inline.
__global__ __launch_bounds__(256) void fproj_kernel(
    const float* __restrict__ qo, const float* __restrict__ ki, const float* __restrict__ vi,
    const float* __restrict__ qw, const float* __restrict__ kw, const float* __restrict__ vw,
    const float* __restrict__ qb, const float* __restrict__ kb, const float* __restrict__ vb,
    ushort* __restrict__ qP, ushort* __restrict__ kP, ushort* __restrict__ vP)
{
  const float* X; const float* Wf; const float* Bias; ushort* Out;
  if (blockIdx.y == 0){ X = qo; Wf = qw; Bias = qb; Out = qP; }
  else if (blockIdx.y == 1){ X = ki; Wf = kw; Bias = kb; Out = kP; }
  else { X = vi; Wf = vw; Bias = vb; Out = vP; }

  __shared__ ushort Xs[HWT][XSTR];

  const int tid = threadIdx.x;
  const int hw0 = blockIdx.x * HWT;

  // ---- stage: X[c][hw] fp32 -> Xs[hwL][c] bf16 ----
  {
    int hwL = tid & 31;
    int cb  = tid >> 5;              // 0..7, owns c in [cb*32, cb*32+32)
    int hw  = hw0 + hwL;
    bool ok = hw < HW;
    const float* Xp = X + (size_t)(cb*32)*HW + (ok ? hw : 0);
    #pragma unroll
    for (int g = 0; g < 4; g++){
      short8 pk;
      #pragma unroll
      for (int u = 0; u < 8; u++){
        float f = ok ? Xp[(size_t)(g*8 + u)*HW] : 0.f;
        pk[u] = (short)f2bf(f);
      }
      *(short8*)(&Xs[hwL][cb*32 + g*8]) = pk;
    }
  }
  __syncthreads();

  const int lane = tid & 63;
  const int wave = tid >> 6;
  const int lm = lane & 15;
  const int lq = lane >> 4;
  const int kout_w = wave * 64;

  const float* Apf = Wf + (size_t)(kout_w + lm)*CH + lq*8;

  floatx4 acc[4][2];
  #pragma unroll
  for (int i = 0; i < 4; i++)
    #pragma unroll
    for (int j = 0; j < 2; j++) acc[i][j] = (floatx4){0,0,0,0};

  #pragma unroll
  for (int k0 = 0; k0 < 8; k0++){
    short8 a[4], b[2];
    #pragma unroll
    for (int i = 0; i < 4; i++){
      const float* p = Apf + (size_t)i*16*CH + k0*32;
      float4 w0 = *(const float4*)p;
      float4 w1 = *(const float4*)(p + 4);
      a[i][0] = (short)f2bf(w0.x); a[i][1] = (short)f2bf(w0.y);
      a[i][2] = (short)f2bf(w0.z); a[i][3] = (short)f2bf(w0.w);
      a[i][4] = (short)f2bf(w1.x); a[i][5] = (short)f2bf(w1.y);
      a[i][6] = (short)f2bf(w1.z); a[i][7] = (short)f2bf(w1.w);
    }
    #pragma unroll
    for (int j = 0; j < 2; j++)
      b[j] = *(const short8*)(&Xs[j*16 + lm][lq*8 + k0*32]);
    #pragma unroll
    for (int i = 0; i < 4; i++)
      #pragma unroll
      for (int j = 0; j < 2; j++)
        acc[i][j] = __builtin_amdgcn_mfma_f32_16x16x32_bf16(a[i], b[j], acc[i][j], 0, 0, 0);
  }

  // C/D: col(lane&15)=hw, row(lq*4+r)=kout
  #pragma unroll
  for (int i = 0; i < 4; i++){
    int kout = kout_w + i*16 + lq*4;
    float4 bias = *(const float4*)(Bias + kout);
    #pragma unroll
    for (int j = 0; j < 2; j++){
      int hw = hw0 + j*16 + lm;
      if (hw < HW){
        ushort4 o;
        o.x = f2bf(acc[i][j][0] + bias.x);
        o.y = f2bf(acc[i][j][1] + bias.y);
        o.z = f2bf(acc[i][j][2] + bias.z);
        o.w = f2bf(acc[i][j][3] + bias.w);
        *(ushort4*)(Out + (size_t)hw*CH + kout) = o;
      }
    }
  }
}

// Block per (t,wo). Lane = (visit-slot g=lane>>4, channel-group gl=lane&15):
// 16 visit-slots/block, 16 channels/lane, 4 shuffle levels/dot.
__global__ __launch_bounds__(256) void attn_kernel(
    const ushort* __restrict__ qP, const ushort* __restrict__ kP, const ushort* __restrict__ vP,
    const float* __restrict__ quad_w, const int* __restrict__ row_ids,
    const int* __restrict__ col_idx, int nnz, float* __restrict__ out)
{
  const int bid  = blockIdx.x;
  const int xcd  = bid & 7;
  const int slot = bid >> 3;

  int t, wo;
  if (slot < 45){
    int hu   = xcd * 45 + slot;
    int hidx = hu / 90;
    t  = (hidx < 2) ? hidx : 42 + hidx;
    wo = hu - hidx * 90;
  } else {
    int lu = xcd * LIGHT_PER_XCD + (slot - 45);
    if (lu >= 42 * NLON) return;
    int li = lu / NLON;
    t  = li + 2;
    wo = lu - li * NLON;
  }

  const int tid  = threadIdx.x;
  const int lane = tid & 63;
  const int wave = tid >> 6;
  const int g    = lane >> 4;
  const int gl   = lane & 15;

  const int start = lower_bound_i(row_ids, nnz, t);
  const int end   = lower_bound_i(row_ids, nnz, t + 1);

  // q channels [gl*16, gl*16+16)
  float qf[16];
  {
    const ushort* qrow = qP + (size_t)(t * NLON + wo) * CH + gl*16;
    short8 q0 = *(const short8*)(qrow);
    short8 q1 = *(const short8*)(qrow + 8);
    #pragma unroll
    for (int u = 0; u < 8; u++){ qf[u] = bf2fs(q0[u]); qf[8+u] = bf2fs(q1[u]); }
  }

  float den = 0.f;
  float acc[16];
  #pragma unroll
  for (int u = 0; u < 16; u++) acc[u] = 0.f;

  for (int n0 = start + wave*4 + g; n0 < end; n0 += 16){
    int ci = col_idx[n0];
    int hi = ci / NLON;
    int wi = ci - hi*NLON + wo; if (wi >= NLON) wi -= NLON;
    size_t off = ((size_t)hi*NLON + wi) * CH + gl*16;

    const short8* kp8 = (const short8*)(kP + off);
    short8 k0 = kp8[0], k1 = kp8[1];
    float s = 0.f;
    #pragma unroll
    for (int u = 0; u < 8; u++){
      s += qf[u]   * bf2fs(k0[u]);
      s += qf[8+u] * bf2fs(k1[u]);
    }
    s += __shfl_xor(s, 1, 64);
    s += __shfl_xor(s, 2, 64);
    s += __shfl_xor(s, 4, 64);
    s += __shfl_xor(s, 8, 64);

    float e = __expf(s) * quad_w[hi];
    const short8* vp8 = (const short8*)(vP + off);
    short8 v0 = vp8[0], v1 = vp8[1];
    den += e;
    #pragma unroll
    for (int u = 0; u < 8; u++){
      acc[u]   += e * bf2fs(v0[u]);
      acc[8+u] += e * bf2fs(v1[u]);
    }
  }

  // merge the 4 visit-slots within the wave
  #pragma unroll
  for (int u = 0; u < 16; u++){
    acc[u] += __shfl_xor(acc[u], 16, 64);
    acc[u] += __shfl_xor(acc[u], 32, 64);
  }
  den += __shfl_xor(den, 16, 64);
  den += __shfl_xor(den, 32, 64);

  __shared__ float sden[4];
  __shared__ float sacc[4][CH];
  if (lane == 0) sden[wave] = den;
  if (g == 0){
    #pragma unroll
    for (int u = 0; u < 16; u++) sacc[wave][gl*16 + u] = acc[u];
  }
  __syncthreads();

  const float D   = sden[0] + sden[1] + sden[2] + sden[3];
  const float num = sacc[0][tid] + sacc[1][tid] + sacc[2][tid] + sacc[3][tid];
  out[(size_t)tid * HW + t * NLON + wo] = num / D;
}

extern "C" void kernel_launch(void* const* d_in, const int* in_sizes, int n_in,
                              void* d_out, int out_size, void* d_ws, size_t ws_size,
                              hipStream_t stream)
{
  const float* qo   = (const float*)d_in[0];
  const float* ki   = (const float*)d_in[1];
  const float* vi   = (const float*)d_in[2];
  const float* qw   = (const float*)d_in[3];
  const float* kw   = (const float*)d_in[4];
  const float* vw   = (const float*)d_in[5];
  const float* qb   = (const float*)d_in[6];
  const float* kb   = (const float*)d_in[7];
  const float* vb   = (const float*)d_in[8];
  const float* quad = (const float*)d_in[9];
  const int* row_ids = (const int*)d_in[10];
  const int* col_idx = (const int*)d_in[11];
  const int nnz = in_sizes[10];

  ushort* ws = (ushort*)d_ws;
  const size_t TSZ = (size_t)HWP * CH;
  ushort* qP = ws;  ushort* kP = qP + TSZ;  ushort* vP = kP + TSZ;

  fproj_kernel<<<dim3(NHT, 3), 256, 0, stream>>>(qo, ki, vi, qw, kw, vw, qb, kb, vb, qP, kP, vP);
  attn_kernel<<<dim3(8 * SLOTS_PER_XCD), 256, 0, stream>>>(qP, kP, vP, quad, row_ids, col_idx, nnz, (float*)d_out);
}